// Round 10
// baseline (199.311 us; speedup 1.0000x reference)
//
#include <hip/hip_runtime.h>

#define EMBED 1024
#define NTOK  4096
#define MARGIN 256.0f   // i8 cheap-logit error sigma ~22; 2*5.5sigma + window
#define KC     8        // candidate slots per (row, wave-tile)
#define WSLOTS 32       // wave-tile slots per row (grid.x * 2)
#define CAP    128      // final per-row candidate cap

// i8 scales: Xi8 = round(X * 127/5), Qi8 = round(Q' * 127/8192)
#define SX_INV 25.4f
#define SQ_INV 0.0155029296875f
#define SCLOGIT 0.07936198f   // (8192/127)*(5/127)/32

typedef short  s16x8 __attribute__((ext_vector_type(8)));
typedef float  f32x4 __attribute__((ext_vector_type(4)));
typedef int    i32x4 __attribute__((ext_vector_type(4)));

// ---- bf16 helpers (RNE) ----------------------------------------------------
__device__ __forceinline__ unsigned short f2bf(float f) {
    unsigned int u = __float_as_uint(f);
    u = (u + 0x7FFFu + ((u >> 16) & 1u)) >> 16;
    return (unsigned short)u;
}
__device__ __forceinline__ float bf2f(unsigned short h) {
    return __uint_as_float(((unsigned int)h) << 16);
}

// ---- async 16B global->LDS -------------------------------------------------
__device__ __forceinline__ void async16(const void* g, void* l) {
    __builtin_amdgcn_global_load_lds(
        (const __attribute__((address_space(1))) unsigned int*)g,
        (__attribute__((address_space(3))) unsigned int*)l, 16, 0, 0);
}

// Stage ROWS x 64-byte rows (row-major, swizzled 16B chunks) into LDS.
// ld in BYTES.
template<int ROWS>
__device__ __forceinline__ void stage_rows(const char* __restrict__ g,
                                           int ld, char* lds, int wave, int lane) {
#pragma unroll
    for (int r = 0; r < ROWS / 64; ++r) {
        const int row0 = (wave * (ROWS / 64) + r) * 16;   // wave-uniform
        const int r_loc = lane >> 2;
        const int kc = (lane - (lane >> 3)) & 3;          // (slot - r_loc/2) & 3
        const char* gp = g + (size_t)(row0 + r_loc) * ld + kc * 16;
        char* lp = lds + row0 * 64;                       // wave-uniform base
        async16(gp, lp);
    }
}

__device__ __forceinline__ int frag_slot(int row, int kc) {
    return (kc + ((row & 15) >> 1)) & 3;
}
__device__ __forceinline__ s16x8 frag_bf16(const char* lds, int row, int kc) {
    return *(const s16x8*)(lds + row * 64 + frag_slot(row, kc) * 16);
}
__device__ __forceinline__ i32x4 frag_i8(const char* lds, int row, int kc) {
    return *(const i32x4*)(lds + row * 64 + frag_slot(row, kc) * 16);
}

// ---------------------------------------------------------------------------
// MFMA bf16 GEMM: C[M,N] = scale * A[M,K] @ B[N,K]^T  (fp32 acc)
// SPLIT==3: 3-pass split-bf16 (hh + hl + lh).  NCH: 32-K chunks per barrier.
// EPI==1: split bf16 (Chi,Clo).  EPI==2: fp32 C + i8 Ci8 (scale SQ_INV).
// ---------------------------------------------------------------------------
template<int BM, int BN, int SPLIT, int EPI, int NCH>
__global__ __launch_bounds__(256) void gemm_mfma(
        const unsigned short* __restrict__ Ahi, const unsigned short* __restrict__ Alo,
        const unsigned short* __restrict__ Bhi, const unsigned short* __restrict__ Blo,
        float* __restrict__ C, unsigned short* __restrict__ Chi,
        unsigned short* __restrict__ Clo, signed char* __restrict__ Ci8,
        int K, int lda, int ldb, int ldc, float scale)
{
    constexpr int TM = BM / 2, TN = BN / 2;
    constexpr int IM = TM / 16, IN = TN / 16;

    __shared__ __align__(16) char As_hi[BM * 64 * NCH];
    __shared__ __align__(16) char Bs_hi[BN * 64 * NCH];
    __shared__ __align__(16) char As_lo[SPLIT == 3 ? BM * 64 * NCH : 16];
    __shared__ __align__(16) char Bs_lo[SPLIT == 3 ? BN * 64 * NCH : 16];

    const int t = threadIdx.x;
    const int lane = t & 63, wave = t >> 6;
    const int wm = wave >> 1, wn = wave & 1;
    const int m0 = blockIdx.y * BM, n0 = blockIdx.x * BN;

    f32x4 acc[IM][IN];
#pragma unroll
    for (int i = 0; i < IM; ++i)
#pragma unroll
        for (int j = 0; j < IN; ++j)
#pragma unroll
            for (int r = 0; r < 4; ++r) acc[i][j][r] = 0.f;

    const char* ah_g = (const char*)(Ahi + (size_t)m0 * lda);
    const char* bh_g = (const char*)(Bhi + (size_t)n0 * ldb);
    const char* al_g = (SPLIT == 3) ? (const char*)(Alo + (size_t)m0 * lda) : nullptr;
    const char* bl_g = (SPLIT == 3) ? (const char*)(Blo + (size_t)n0 * ldb) : nullptr;

    const int kc = lane >> 4;
    const int rr = lane & 15;

    for (int k0 = 0; k0 < K; k0 += 32 * NCH) {
#pragma unroll
        for (int c = 0; c < NCH; ++c) {
            const int kb = (k0 + 32 * c) * 2;
            stage_rows<BM>(ah_g + kb, lda * 2, As_hi + c * BM * 64, wave, lane);
            stage_rows<BN>(bh_g + kb, ldb * 2, Bs_hi + c * BN * 64, wave, lane);
            if constexpr (SPLIT == 3) {
                stage_rows<BM>(al_g + kb, lda * 2, As_lo + c * BM * 64, wave, lane);
                stage_rows<BN>(bl_g + kb, ldb * 2, Bs_lo + c * BN * 64, wave, lane);
            }
        }
        __syncthreads();

#pragma unroll
        for (int c = 0; c < NCH; ++c) {
            s16x8 ah[IM], bh[IN], al[IM], bl[IN];
#pragma unroll
            for (int i = 0; i < IM; ++i)
                ah[i] = frag_bf16(As_hi + c * BM * 64, wm * TM + i * 16 + rr, kc);
#pragma unroll
            for (int j = 0; j < IN; ++j)
                bh[j] = frag_bf16(Bs_hi + c * BN * 64, wn * TN + j * 16 + rr, kc);
            if constexpr (SPLIT == 3) {
#pragma unroll
                for (int i = 0; i < IM; ++i)
                    al[i] = frag_bf16(As_lo + c * BM * 64, wm * TM + i * 16 + rr, kc);
#pragma unroll
                for (int j = 0; j < IN; ++j)
                    bl[j] = frag_bf16(Bs_lo + c * BN * 64, wn * TN + j * 16 + rr, kc);
            }

#pragma unroll
            for (int i = 0; i < IM; ++i)
#pragma unroll
                for (int j = 0; j < IN; ++j)
                    acc[i][j] = __builtin_amdgcn_mfma_f32_16x16x32_bf16(ah[i], bh[j], acc[i][j], 0, 0, 0);
            if constexpr (SPLIT == 3) {
#pragma unroll
                for (int i = 0; i < IM; ++i)
#pragma unroll
                    for (int j = 0; j < IN; ++j)
                        acc[i][j] = __builtin_amdgcn_mfma_f32_16x16x32_bf16(ah[i], bl[j], acc[i][j], 0, 0, 0);
#pragma unroll
                for (int i = 0; i < IM; ++i)
#pragma unroll
                    for (int j = 0; j < IN; ++j)
                        acc[i][j] = __builtin_amdgcn_mfma_f32_16x16x32_bf16(al[i], bh[j], acc[i][j], 0, 0, 0);
            }
        }
        __syncthreads();
    }

    // Epilogue: C/D layout col=lane&15, row=(lane>>4)*4+reg
    const int lr = lane >> 4;
    const int lc = lane & 15;
#pragma unroll
    for (int i = 0; i < IM; ++i)
#pragma unroll
        for (int j = 0; j < IN; ++j)
#pragma unroll
            for (int r = 0; r < 4; ++r) {
                const int row = m0 + wm * TM + i * 16 + lr * 4 + r;
                const int col = n0 + wn * TN + j * 16 + lc;
                const float v = acc[i][j][r] * scale;
                const size_t idx = (size_t)row * ldc + col;
                if constexpr (EPI == 1) {
                    const unsigned short h = f2bf(v);
                    Chi[idx] = h;
                    Clo[idx] = f2bf(v - bf2f(h));
                } else {
                    C[idx] = v;
                    const float q = fminf(fmaxf(v * SQ_INV, -127.f), 127.f);
                    Ci8[idx] = (signed char)(int)rintf(q);
                }
            }
}

// ---------------------------------------------------------------------------
// i8 scores GEMM + write-only candidate selection.
// Tile 128x256, BK=64, grid (16,32) = 512 blocks (2/CU). Wave tile 64x128.
// ---------------------------------------------------------------------------
__global__ __launch_bounds__(256) void gemm_i8_scores(
        const signed char* __restrict__ A,   // Qi8 [NTOK, EMBED]
        const signed char* __restrict__ B,   // Xi8 [NTOK, EMBED]
        float* __restrict__ tmax, int* __restrict__ cnts, int2* __restrict__ cand)
{
    __shared__ __align__(16) char As[128 * 64];
    __shared__ __align__(16) char Bs[256 * 64];

    const int t = threadIdx.x;
    const int lane = t & 63, wave = t >> 6;
    const int wm = wave >> 1, wn = wave & 1;
    const int m0 = blockIdx.y * 128, n0 = blockIdx.x * 256;

    i32x4 acc[4][8];
#pragma unroll
    for (int i = 0; i < 4; ++i)
#pragma unroll
        for (int j = 0; j < 8; ++j)
#pragma unroll
            for (int r = 0; r < 4; ++r) acc[i][j][r] = 0;

    const char* a_g = (const char*)A + (size_t)m0 * EMBED;
    const char* b_g = (const char*)B + (size_t)n0 * EMBED;
    const int kc = lane >> 4;
    const int rr = lane & 15;

    for (int k0 = 0; k0 < EMBED; k0 += 64) {
        stage_rows<128>(a_g + k0, EMBED, As, wave, lane);
        stage_rows<256>(b_g + k0, EMBED, Bs, wave, lane);
        __syncthreads();

        i32x4 af[4], bf[8];
#pragma unroll
        for (int i = 0; i < 4; ++i) af[i] = frag_i8(As, wm * 64 + i * 16 + rr, kc);
#pragma unroll
        for (int j = 0; j < 8; ++j) bf[j] = frag_i8(Bs, wn * 128 + j * 16 + rr, kc);
#pragma unroll
        for (int i = 0; i < 4; ++i)
#pragma unroll
            for (int j = 0; j < 8; ++j)
                acc[i][j] = __builtin_amdgcn_mfma_i32_16x16x64_i8(af[i], bf[j], acc[i][j], 0, 0, 0);
        __syncthreads();
    }

    // Write-only local selection epilogue.
    const int lr = lane >> 4;
    const int lc = lane & 15;
    const int wslot = blockIdx.x * 2 + wn;                // WSLOTS=32 per row
    const unsigned long long grp = 0xFFFFull << (lr * 16);
    const unsigned long long low = (lane == 63) ? 0x7FFFFFFFFFFFFFFFull
                                                : ((1ull << lane) - 1);
#pragma unroll
    for (int i = 0; i < 4; ++i)
#pragma unroll
        for (int r = 0; r < 4; ++r) {
            const int row = m0 + wm * 64 + i * 16 + lr * 4 + r;
            float v[8];
            float vmax = -3.4e38f;
#pragma unroll
            for (int j = 0; j < 8; ++j) {
                v[j] = (float)acc[i][j][r] * SCLOGIT;
                vmax = fmaxf(vmax, v[j]);
            }
#pragma unroll
            for (int msk = 1; msk < 16; msk <<= 1)
                vmax = fmaxf(vmax, __shfl_xor(vmax, msk, 64));
            const float thr = vmax - MARGIN;
            int base = 0;
#pragma unroll
            for (int j = 0; j < 8; ++j) {
                const bool pred = v[j] > thr;
                const unsigned long long m = __ballot(pred) & grp;
                if (pred) {
                    const int pos = base + __popcll(m & low);
                    if (pos < KC)
                        cand[((size_t)row * WSLOTS + wslot) * KC + pos] =
                            make_int2(n0 + wn * 128 + j * 16 + lc,
                                      __float_as_int(v[j]));
                }
                base += __popcll(m);
            }
            if (lc == 0) {
                tmax[(size_t)row * WSLOTS + wslot] = vmax;
                cnts[(size_t)row * WSLOTS + wslot] = base < KC ? base : KC;
            }
        }
}

// ---------------------------------------------------------------------------
// Fused splits: X -> bf16 hi/lo + i8; Wq, Wk -> bf16 hi/lo. One dispatch.
// ---------------------------------------------------------------------------
__global__ __launch_bounds__(256) void split_all(
        const float4* __restrict__ X, const float4* __restrict__ Wq,
        const float4* __restrict__ Wk,
        ushort4* __restrict__ Xhi, ushort4* __restrict__ Xlo, char4* __restrict__ Xi8,
        ushort4* __restrict__ Wqhi, ushort4* __restrict__ Wqlo,
        ushort4* __restrict__ Wkhi, ushort4* __restrict__ Wklo) {
    const int NX4 = NTOK * EMBED / 4;
    const int NW4 = EMBED * EMBED / 4;
    const int n = blockIdx.x * 256 + threadIdx.x;

    const float4* src;
    ushort4 *hi, *lo;
    int idx;
    bool do_i8 = false;
    if (n < NX4) {
        src = X; hi = Xhi; lo = Xlo; idx = n; do_i8 = true;
    } else if (n < NX4 + NW4) {
        src = Wq; hi = Wqhi; lo = Wqlo; idx = n - NX4;
    } else {
        src = Wk; hi = Wkhi; lo = Wklo; idx = n - NX4 - NW4;
    }
    const float4 v = src[idx];
    ushort4 h, l;
    h.x = f2bf(v.x); l.x = f2bf(v.x - bf2f(h.x));
    h.y = f2bf(v.y); l.y = f2bf(v.y - bf2f(h.y));
    h.z = f2bf(v.z); l.z = f2bf(v.z - bf2f(h.z));
    h.w = f2bf(v.w); l.w = f2bf(v.w - bf2f(h.w));
    hi[idx] = h; lo[idx] = l;
    if (do_i8) {
        char4 c;
        c.x = (signed char)(int)rintf(fminf(fmaxf(v.x * SX_INV, -127.f), 127.f));
        c.y = (signed char)(int)rintf(fminf(fmaxf(v.y * SX_INV, -127.f), 127.f));
        c.z = (signed char)(int)rintf(fminf(fmaxf(v.z * SX_INV, -127.f), 127.f));
        c.w = (signed char)(int)rintf(fminf(fmaxf(v.w * SX_INV, -127.f), 127.f));
        Xi8[idx] = c;
    }
}

// ---------------------------------------------------------------------------
// Final: global row max over WSLOTS tile maxima, filter stored candidates,
// wave-parallel exact fp32 logits, softmax, blend fp32 X rows. 1 block/row.
// ---------------------------------------------------------------------------
__global__ __launch_bounds__(256) void sparse_out(const float* __restrict__ tmax,
                                                  const int* __restrict__ cnts,
                                                  const int2* __restrict__ cand,
                                                  const float* __restrict__ Qf,
                                                  const float* __restrict__ X,
                                                  float* __restrict__ out) {
    const int t = threadIdx.x;
    const int lane = t & 63, wave = t >> 6;
    const int row = blockIdx.x;

    __shared__ float gmax_s;
    __shared__ int   n2;
    __shared__ int   list[CAP];
    __shared__ float ll[CAP];
    if (t == 0) n2 = 0;

    // global row max over WSLOTS tile maxima (wave 0)
    float gm = -3.4e38f;
    if (t < WSLOTS) gm = tmax[(size_t)row * WSLOTS + t];
#pragma unroll
    for (int off = 32; off >= 1; off >>= 1) gm = fmaxf(gm, __shfl_xor(gm, off, 64));
    if (t == 0) gmax_s = gm;
    __syncthreads();
    const float thr = gmax_s - MARGIN;

    // filter stored candidates (WSLOTS slots x KC entries)
    for (int e = t; e < WSLOTS * KC; e += 256) {
        const int s = e >> 3, k = e & (KC - 1);
        if (k < cnts[(size_t)row * WSLOTS + s]) {
            const int2 c = cand[((size_t)row * WSLOTS + s) * KC + k];
            if (__int_as_float(c.y) > thr) {
                const int p = atomicAdd(&n2, 1);   // LDS atomic
                if (p < CAP) list[p] = c.x;
            }
        }
    }
    __syncthreads();
    const int nc = min(n2, CAP);

    // exact logits, wave-parallel: candidate c handled by wave (c & 3)
    float4 q[4];
#pragma unroll
    for (int i = 0; i < 4; ++i)
        q[i] = *(const float4*)&Qf[(size_t)row * EMBED + lane * 16 + i * 4];
    for (int c = wave; c < nc; c += 4) {
        const float* xp = &X[(size_t)list[c] * EMBED + lane * 16];
        float p = 0.f;
#pragma unroll
        for (int i = 0; i < 4; ++i) {
            const float4 x4 = *(const float4*)(xp + i * 4);
            p += q[i].x * x4.x + q[i].y * x4.y + q[i].z * x4.z + q[i].w * x4.w;
        }
#pragma unroll
        for (int off = 32; off >= 1; off >>= 1) p += __shfl_xor(p, off, 64);
        if (lane == 0) ll[c] = p * 0.03125f;
    }
    __syncthreads();

    // exact softmax over candidates (redundant per thread; nc is tiny)
    float mt = -3.4e38f;
    for (int c = 0; c < nc; ++c) mt = fmaxf(mt, ll[c]);
    float wsum = 0.f;
    for (int c = 0; c < nc; ++c) wsum += __expf(ll[c] - mt);
    const float inv = 1.0f / wsum;

    float4 o = {0.f, 0.f, 0.f, 0.f};
    for (int c = 0; c < nc; ++c) {
        const float w = __expf(ll[c] - mt);
        const float4 xj = *(const float4*)&X[(size_t)list[c] * EMBED + t * 4];
        o.x += w * xj.x; o.y += w * xj.y; o.z += w * xj.z; o.w += w * xj.w;
    }
    o.x *= inv; o.y *= inv; o.z *= inv; o.w *= inv;
    *(float4*)&out[(size_t)row * EMBED + t * 4] = o;
}

extern "C" void kernel_launch(void* const* d_in, const int* in_sizes, int n_in,
                              void* d_out, int out_size, void* d_ws, size_t ws_size,
                              hipStream_t stream) {
    const float* X  = (const float*)d_in[0];  // [4096,1024]
    const float* Wq = (const float*)d_in[1];  // [1024,1024]
    const float* Wk = (const float*)d_in[2];  // [1024,1024]
    float* out = (float*)d_out;

    char* ws = (char*)d_ws;
    const size_t MB = 1024 * 1024;
    unsigned short* Xhi = (unsigned short*)(ws + 0 * MB);   // 8 MB
    unsigned short* Xlo = (unsigned short*)(ws + 8 * MB);   // 8 MB
    signed char*    Xi8 = (signed char*)(ws + 16 * MB);     // 4 MB
    float*          Qf  = (float*)(ws + 20 * MB);           // 16 MB
    signed char*    Qi8 = (signed char*)(ws + 36 * MB);     // 4 MB
    float* tmax = (float*)(ws + 40 * MB);                   // 0.5 MB
    int*   cnts = (int*)(ws + 41 * MB);                     // 0.5 MB
    int2*  cand = (int2*)(ws + 42 * MB);                    // 8 MB
    unsigned short* Wqhi = (unsigned short*)(ws + 58 * MB);
    unsigned short* Wqlo = (unsigned short*)(ws + 60 * MB);
    unsigned short* Wkhi = (unsigned short*)(ws + 62 * MB);
    unsigned short* Wklo = (unsigned short*)(ws + 64 * MB);
    unsigned short* Thi  = (unsigned short*)(ws + 66 * MB);
    unsigned short* Tlo  = (unsigned short*)(ws + 68 * MB);

    // 1) fused splits (X -> hi/lo/i8, Wq/Wk -> hi/lo)
    split_all<<<6144, 256, 0, stream>>>(
        (const float4*)X, (const float4*)Wq, (const float4*)Wk,
        (ushort4*)Xhi, (ushort4*)Xlo, (char4*)Xi8,
        (ushort4*)Wqhi, (ushort4*)Wqlo, (ushort4*)Wkhi, (ushort4*)Wklo);

    // 2) T = Wk @ Wq^T (= M^T), 3-pass split, BK=64 -> split bf16
    gemm_mfma<64, 64, 3, 1, 2><<<dim3(16, 16), 256, 0, stream>>>(
        Wkhi, Wklo, Wqhi, Wqlo, nullptr, Thi, Tlo, nullptr,
        EMBED, EMBED, EMBED, EMBED, 1.0f);

    // 3) Qf = X @ T^T (= X @ M), 3-pass split, BM=128 (measured-best tile)
    gemm_mfma<128, 64, 3, 2, 2><<<dim3(16, 32), 256, 0, stream>>>(
        Xhi, Xlo, Thi, Tlo, Qf, nullptr, nullptr, Qi8,
        EMBED, EMBED, EMBED, EMBED, 1.0f);

    // 4) i8 cheap scores, 128x256 tile + write-only candidate selection
    gemm_i8_scores<<<dim3(16, 32), 256, 0, stream>>>(Qi8, Xi8, tmax, cnts, cand);

    // 5) exact sparse softmax + gather
    sparse_out<<<NTOK, 256, 0, stream>>>(tmax, cnts, cand, Qf, X, out);
}

// Round 11
// 184.558 us; speedup vs baseline: 1.0799x; 1.0799x over previous
//
#include <hip/hip_runtime.h>

#define EMBED 1024
#define NTOK  4096
#define MARGIN 256.0f   // i8 cheap-logit error sigma ~22; 2*5.5sigma + window
#define KC     8        // candidate slots per (row, wave-tile)
#define CAP    128      // final per-row candidate cap

// i8 scales: Xi8 = round(X * 127/5), Qi8 = round(Q' * 127/8192)
#define SX_INV 25.4f
#define SQ_INV 0.0155029296875f
#define SCLOGIT 0.07936198f   // (8192/127)*(5/127)/32

typedef short  s16x8 __attribute__((ext_vector_type(8)));
typedef float  f32x4 __attribute__((ext_vector_type(4)));
typedef int    i32x4 __attribute__((ext_vector_type(4)));

// ---- bf16 helpers (RNE) ----------------------------------------------------
__device__ __forceinline__ unsigned short f2bf(float f) {
    unsigned int u = __float_as_uint(f);
    u = (u + 0x7FFFu + ((u >> 16) & 1u)) >> 16;
    return (unsigned short)u;
}
__device__ __forceinline__ float bf2f(unsigned short h) {
    return __uint_as_float(((unsigned int)h) << 16);
}

// ---- async 16B global->LDS -------------------------------------------------
__device__ __forceinline__ void async16(const void* g, void* l) {
    __builtin_amdgcn_global_load_lds(
        (const __attribute__((address_space(1))) unsigned int*)g,
        (__attribute__((address_space(3))) unsigned int*)l, 16, 0, 0);
}

// Stage ROWS x 64-byte rows (row-major, swizzled 16B chunks) into LDS.
// ld in BYTES.
template<int ROWS>
__device__ __forceinline__ void stage_rows(const char* __restrict__ g,
                                           int ld, char* lds, int wave, int lane) {
#pragma unroll
    for (int r = 0; r < ROWS / 64; ++r) {
        const int row0 = (wave * (ROWS / 64) + r) * 16;   // wave-uniform
        const int r_loc = lane >> 2;
        const int kc = (lane - (lane >> 3)) & 3;          // (slot - r_loc/2) & 3
        const char* gp = g + (size_t)(row0 + r_loc) * ld + kc * 16;
        char* lp = lds + row0 * 64;                       // wave-uniform base
        async16(gp, lp);
    }
}

__device__ __forceinline__ int frag_slot(int row, int kc) {
    return (kc + ((row & 15) >> 1)) & 3;
}
__device__ __forceinline__ s16x8 frag_bf16(const char* lds, int row, int kc) {
    return *(const s16x8*)(lds + row * 64 + frag_slot(row, kc) * 16);
}
__device__ __forceinline__ i32x4 frag_i8(const char* lds, int row, int kc) {
    return *(const i32x4*)(lds + row * 64 + frag_slot(row, kc) * 16);
}

// ---------------------------------------------------------------------------
// MFMA bf16 GEMM: C[M,N] = scale * A[M,K] @ B[N,K]^T  (fp32 acc)
// SPLIT==3: 3-pass split-bf16 (hh + hl + lh).  NCH: 32-K chunks per barrier.
// EPI==1: split bf16 (Chi,Clo).  EPI==2: fp32 C + i8 Ci8 (scale SQ_INV).
// ---------------------------------------------------------------------------
template<int BM, int BN, int SPLIT, int EPI, int NCH>
__global__ __launch_bounds__(256) void gemm_mfma(
        const unsigned short* __restrict__ Ahi, const unsigned short* __restrict__ Alo,
        const unsigned short* __restrict__ Bhi, const unsigned short* __restrict__ Blo,
        float* __restrict__ C, unsigned short* __restrict__ Chi,
        unsigned short* __restrict__ Clo, signed char* __restrict__ Ci8,
        int K, int lda, int ldb, int ldc, float scale)
{
    constexpr int TM = BM / 2, TN = BN / 2;
    constexpr int IM = TM / 16, IN = TN / 16;

    __shared__ __align__(16) char As_hi[BM * 64 * NCH];
    __shared__ __align__(16) char Bs_hi[BN * 64 * NCH];
    __shared__ __align__(16) char As_lo[SPLIT == 3 ? BM * 64 * NCH : 16];
    __shared__ __align__(16) char Bs_lo[SPLIT == 3 ? BN * 64 * NCH : 16];

    const int t = threadIdx.x;
    const int lane = t & 63, wave = t >> 6;
    const int wm = wave >> 1, wn = wave & 1;
    const int m0 = blockIdx.y * BM, n0 = blockIdx.x * BN;

    f32x4 acc[IM][IN];
#pragma unroll
    for (int i = 0; i < IM; ++i)
#pragma unroll
        for (int j = 0; j < IN; ++j)
#pragma unroll
            for (int r = 0; r < 4; ++r) acc[i][j][r] = 0.f;

    const char* ah_g = (const char*)(Ahi + (size_t)m0 * lda);
    const char* bh_g = (const char*)(Bhi + (size_t)n0 * ldb);
    const char* al_g = (SPLIT == 3) ? (const char*)(Alo + (size_t)m0 * lda) : nullptr;
    const char* bl_g = (SPLIT == 3) ? (const char*)(Blo + (size_t)n0 * ldb) : nullptr;

    const int kc = lane >> 4;
    const int rr = lane & 15;

    for (int k0 = 0; k0 < K; k0 += 32 * NCH) {
#pragma unroll
        for (int c = 0; c < NCH; ++c) {
            const int kb = (k0 + 32 * c) * 2;
            stage_rows<BM>(ah_g + kb, lda * 2, As_hi + c * BM * 64, wave, lane);
            stage_rows<BN>(bh_g + kb, ldb * 2, Bs_hi + c * BN * 64, wave, lane);
            if constexpr (SPLIT == 3) {
                stage_rows<BM>(al_g + kb, lda * 2, As_lo + c * BM * 64, wave, lane);
                stage_rows<BN>(bl_g + kb, ldb * 2, Bs_lo + c * BN * 64, wave, lane);
            }
        }
        __syncthreads();

#pragma unroll
        for (int c = 0; c < NCH; ++c) {
            s16x8 ah[IM], bh[IN], al[IM], bl[IN];
#pragma unroll
            for (int i = 0; i < IM; ++i)
                ah[i] = frag_bf16(As_hi + c * BM * 64, wm * TM + i * 16 + rr, kc);
#pragma unroll
            for (int j = 0; j < IN; ++j)
                bh[j] = frag_bf16(Bs_hi + c * BN * 64, wn * TN + j * 16 + rr, kc);
            if constexpr (SPLIT == 3) {
#pragma unroll
                for (int i = 0; i < IM; ++i)
                    al[i] = frag_bf16(As_lo + c * BM * 64, wm * TM + i * 16 + rr, kc);
#pragma unroll
                for (int j = 0; j < IN; ++j)
                    bl[j] = frag_bf16(Bs_lo + c * BN * 64, wn * TN + j * 16 + rr, kc);
            }

#pragma unroll
            for (int i = 0; i < IM; ++i)
#pragma unroll
                for (int j = 0; j < IN; ++j)
                    acc[i][j] = __builtin_amdgcn_mfma_f32_16x16x32_bf16(ah[i], bh[j], acc[i][j], 0, 0, 0);
            if constexpr (SPLIT == 3) {
#pragma unroll
                for (int i = 0; i < IM; ++i)
#pragma unroll
                    for (int j = 0; j < IN; ++j)
                        acc[i][j] = __builtin_amdgcn_mfma_f32_16x16x32_bf16(ah[i], bl[j], acc[i][j], 0, 0, 0);
#pragma unroll
                for (int i = 0; i < IM; ++i)
#pragma unroll
                    for (int j = 0; j < IN; ++j)
                        acc[i][j] = __builtin_amdgcn_mfma_f32_16x16x32_bf16(al[i], bh[j], acc[i][j], 0, 0, 0);
            }
        }
        __syncthreads();
    }

    // Epilogue: C/D layout col=lane&15, row=(lane>>4)*4+reg
    const int lr = lane >> 4;
    const int lc = lane & 15;
#pragma unroll
    for (int i = 0; i < IM; ++i)
#pragma unroll
        for (int j = 0; j < IN; ++j)
#pragma unroll
            for (int r = 0; r < 4; ++r) {
                const int row = m0 + wm * TM + i * 16 + lr * 4 + r;
                const int col = n0 + wn * TN + j * 16 + lc;
                const float v = acc[i][j][r] * scale;
                const size_t idx = (size_t)row * ldc + col;
                if constexpr (EPI == 1) {
                    const unsigned short h = f2bf(v);
                    Chi[idx] = h;
                    Clo[idx] = f2bf(v - bf2f(h));
                } else {
                    C[idx] = v;
                    const float q = fminf(fmaxf(v * SQ_INV, -127.f), 127.f);
                    Ci8[idx] = (signed char)(int)rintf(q);
                }
            }
}

// ---------------------------------------------------------------------------
// i8 scores GEMM + write-only candidate selection. NCH=2 (128-K per barrier).
// Tile 128x128, grid (32,32) = 1024 blocks — measured-best config (R7).
// ---------------------------------------------------------------------------
__global__ __launch_bounds__(256) void gemm_i8_scores(
        const signed char* __restrict__ A,   // Qi8 [NTOK, EMBED]
        const signed char* __restrict__ B,   // Xi8 [NTOK, EMBED]
        float* __restrict__ tmax, int* __restrict__ cnts, int2* __restrict__ cand)
{
    __shared__ __align__(16) char As[128 * 64 * 2];
    __shared__ __align__(16) char Bs[128 * 64 * 2];

    const int t = threadIdx.x;
    const int lane = t & 63, wave = t >> 6;
    const int wm = wave >> 1, wn = wave & 1;
    const int m0 = blockIdx.y * 128, n0 = blockIdx.x * 128;

    i32x4 acc[4][4];
#pragma unroll
    for (int i = 0; i < 4; ++i)
#pragma unroll
        for (int j = 0; j < 4; ++j)
#pragma unroll
            for (int r = 0; r < 4; ++r) acc[i][j][r] = 0;

    const char* a_g = (const char*)A + (size_t)m0 * EMBED;
    const char* b_g = (const char*)B + (size_t)n0 * EMBED;
    const int kc = lane >> 4;
    const int rr = lane & 15;

    for (int k0 = 0; k0 < EMBED; k0 += 128) {
#pragma unroll
        for (int c = 0; c < 2; ++c) {
            stage_rows<128>(a_g + k0 + 64 * c, EMBED, As + c * 128 * 64, wave, lane);
            stage_rows<128>(b_g + k0 + 64 * c, EMBED, Bs + c * 128 * 64, wave, lane);
        }
        __syncthreads();

#pragma unroll
        for (int c = 0; c < 2; ++c) {
            i32x4 af[4], bf[4];
#pragma unroll
            for (int i = 0; i < 4; ++i) af[i] = frag_i8(As + c * 128 * 64, wm * 64 + i * 16 + rr, kc);
#pragma unroll
            for (int j = 0; j < 4; ++j) bf[j] = frag_i8(Bs + c * 128 * 64, wn * 64 + j * 16 + rr, kc);
#pragma unroll
            for (int i = 0; i < 4; ++i)
#pragma unroll
                for (int j = 0; j < 4; ++j)
                    acc[i][j] = __builtin_amdgcn_mfma_i32_16x16x64_i8(af[i], bf[j], acc[i][j], 0, 0, 0);
        }
        __syncthreads();
    }

    // Write-only local selection epilogue.
    const int lr = lane >> 4;
    const int lc = lane & 15;
    const int wslot = blockIdx.x * 2 + wn;                // 64 slots per row
    const unsigned long long grp = 0xFFFFull << (lr * 16);
    const unsigned long long low = (lane == 63) ? 0x7FFFFFFFFFFFFFFFull
                                                : ((1ull << lane) - 1);
#pragma unroll
    for (int i = 0; i < 4; ++i)
#pragma unroll
        for (int r = 0; r < 4; ++r) {
            const int row = m0 + wm * 64 + i * 16 + lr * 4 + r;
            float v[4];
            float vmax = -3.4e38f;
#pragma unroll
            for (int j = 0; j < 4; ++j) {
                v[j] = (float)acc[i][j][r] * SCLOGIT;
                vmax = fmaxf(vmax, v[j]);
            }
#pragma unroll
            for (int msk = 1; msk < 16; msk <<= 1)
                vmax = fmaxf(vmax, __shfl_xor(vmax, msk, 64));
            const float thr = vmax - MARGIN;
            int base = 0;
#pragma unroll
            for (int j = 0; j < 4; ++j) {
                const bool pred = v[j] > thr;
                const unsigned long long m = __ballot(pred) & grp;
                if (pred) {
                    const int pos = base + __popcll(m & low);
                    if (pos < KC)
                        cand[((size_t)row * 64 + wslot) * KC + pos] =
                            make_int2(n0 + wn * 64 + j * 16 + lc,
                                      __float_as_int(v[j]));
                }
                base += __popcll(m);
            }
            if (lc == 0) {
                tmax[(size_t)row * 64 + wslot] = vmax;
                cnts[(size_t)row * 64 + wslot] = base < KC ? base : KC;
            }
        }
}

// ---------------------------------------------------------------------------
// Fused splits: X -> bf16 hi/lo + i8; Wq, Wk -> bf16 hi/lo. One dispatch.
// ---------------------------------------------------------------------------
__global__ __launch_bounds__(256) void split_all(
        const float4* __restrict__ X, const float4* __restrict__ Wq,
        const float4* __restrict__ Wk,
        ushort4* __restrict__ Xhi, ushort4* __restrict__ Xlo, char4* __restrict__ Xi8,
        ushort4* __restrict__ Wqhi, ushort4* __restrict__ Wqlo,
        ushort4* __restrict__ Wkhi, ushort4* __restrict__ Wklo) {
    const int NX4 = NTOK * EMBED / 4;
    const int NW4 = EMBED * EMBED / 4;
    const int n = blockIdx.x * 256 + threadIdx.x;

    const float4* src;
    ushort4 *hi, *lo;
    int idx;
    bool do_i8 = false;
    if (n < NX4) {
        src = X; hi = Xhi; lo = Xlo; idx = n; do_i8 = true;
    } else if (n < NX4 + NW4) {
        src = Wq; hi = Wqhi; lo = Wqlo; idx = n - NX4;
    } else {
        src = Wk; hi = Wkhi; lo = Wklo; idx = n - NX4 - NW4;
    }
    const float4 v = src[idx];
    ushort4 h, l;
    h.x = f2bf(v.x); l.x = f2bf(v.x - bf2f(h.x));
    h.y = f2bf(v.y); l.y = f2bf(v.y - bf2f(h.y));
    h.z = f2bf(v.z); l.z = f2bf(v.z - bf2f(h.z));
    h.w = f2bf(v.w); l.w = f2bf(v.w - bf2f(h.w));
    hi[idx] = h; lo[idx] = l;
    if (do_i8) {
        char4 c;
        c.x = (signed char)(int)rintf(fminf(fmaxf(v.x * SX_INV, -127.f), 127.f));
        c.y = (signed char)(int)rintf(fminf(fmaxf(v.y * SX_INV, -127.f), 127.f));
        c.z = (signed char)(int)rintf(fminf(fmaxf(v.z * SX_INV, -127.f), 127.f));
        c.w = (signed char)(int)rintf(fminf(fmaxf(v.w * SX_INV, -127.f), 127.f));
        Xi8[idx] = c;
    }
}

// ---------------------------------------------------------------------------
// Final: global row max over 64 tile maxima, filter stored candidates,
// wave-parallel exact fp32 logits, softmax, blend fp32 X rows. 1 block/row.
// ---------------------------------------------------------------------------
__global__ __launch_bounds__(256) void sparse_out(const float* __restrict__ tmax,
                                                  const int* __restrict__ cnts,
                                                  const int2* __restrict__ cand,
                                                  const float* __restrict__ Qf,
                                                  const float* __restrict__ X,
                                                  float* __restrict__ out) {
    const int t = threadIdx.x;
    const int lane = t & 63, wave = t >> 6;
    const int row = blockIdx.x;

    __shared__ float gmax_s;
    __shared__ int   n2;
    __shared__ int   list[CAP];
    __shared__ float ll[CAP];
    if (t == 0) n2 = 0;

    // global row max over 64 tile maxima (wave 0)
    float gm = -3.4e38f;
    if (t < 64) gm = tmax[(size_t)row * 64 + t];
#pragma unroll
    for (int off = 32; off >= 1; off >>= 1) gm = fmaxf(gm, __shfl_xor(gm, off, 64));
    if (t == 0) gmax_s = gm;
    __syncthreads();
    const float thr = gmax_s - MARGIN;

    // filter stored candidates (64 slots x KC entries)
    for (int e = t; e < 64 * KC; e += 256) {
        const int s = e >> 3, k = e & (KC - 1);
        if (k < cnts[(size_t)row * 64 + s]) {
            const int2 c = cand[((size_t)row * 64 + s) * KC + k];
            if (__int_as_float(c.y) > thr) {
                const int p = atomicAdd(&n2, 1);   // LDS atomic
                if (p < CAP) list[p] = c.x;
            }
        }
    }
    __syncthreads();
    const int nc = min(n2, CAP);

    // exact logits, wave-parallel: candidate c handled by wave (c & 3)
    float4 q[4];
#pragma unroll
    for (int i = 0; i < 4; ++i)
        q[i] = *(const float4*)&Qf[(size_t)row * EMBED + lane * 16 + i * 4];
    for (int c = wave; c < nc; c += 4) {
        const float* xp = &X[(size_t)list[c] * EMBED + lane * 16];
        float p = 0.f;
#pragma unroll
        for (int i = 0; i < 4; ++i) {
            const float4 x4 = *(const float4*)(xp + i * 4);
            p += q[i].x * x4.x + q[i].y * x4.y + q[i].z * x4.z + q[i].w * x4.w;
        }
#pragma unroll
        for (int off = 32; off >= 1; off >>= 1) p += __shfl_xor(p, off, 64);
        if (lane == 0) ll[c] = p * 0.03125f;
    }
    __syncthreads();

    // exact softmax over candidates (redundant per thread; nc is tiny)
    float mt = -3.4e38f;
    for (int c = 0; c < nc; ++c) mt = fmaxf(mt, ll[c]);
    float wsum = 0.f;
    for (int c = 0; c < nc; ++c) wsum += __expf(ll[c] - mt);
    const float inv = 1.0f / wsum;

    float4 o = {0.f, 0.f, 0.f, 0.f};
    for (int c = 0; c < nc; ++c) {
        const float w = __expf(ll[c] - mt);
        const float4 xj = *(const float4*)&X[(size_t)list[c] * EMBED + t * 4];
        o.x += w * xj.x; o.y += w * xj.y; o.z += w * xj.z; o.w += w * xj.w;
    }
    o.x *= inv; o.y *= inv; o.z *= inv; o.w *= inv;
    *(float4*)&out[(size_t)row * EMBED + t * 4] = o;
}

extern "C" void kernel_launch(void* const* d_in, const int* in_sizes, int n_in,
                              void* d_out, int out_size, void* d_ws, size_t ws_size,
                              hipStream_t stream) {
    const float* X  = (const float*)d_in[0];  // [4096,1024]
    const float* Wq = (const float*)d_in[1];  // [1024,1024]
    const float* Wk = (const float*)d_in[2];  // [1024,1024]
    float* out = (float*)d_out;

    char* ws = (char*)d_ws;
    const size_t MB = 1024 * 1024;
    unsigned short* Xhi = (unsigned short*)(ws + 0 * MB);   // 8 MB
    unsigned short* Xlo = (unsigned short*)(ws + 8 * MB);   // 8 MB
    signed char*    Xi8 = (signed char*)(ws + 16 * MB);     // 4 MB
    float*          Qf  = (float*)(ws + 20 * MB);           // 16 MB
    signed char*    Qi8 = (signed char*)(ws + 36 * MB);     // 4 MB
    float* tmax = (float*)(ws + 40 * MB);                   // 1 MB
    int*   cnts = (int*)(ws + 41 * MB);                     // 1 MB
    int2*  cand = (int2*)(ws + 42 * MB);                    // 16 MB
    unsigned short* Wqhi = (unsigned short*)(ws + 58 * MB);
    unsigned short* Wqlo = (unsigned short*)(ws + 60 * MB);
    unsigned short* Wkhi = (unsigned short*)(ws + 62 * MB);
    unsigned short* Wklo = (unsigned short*)(ws + 64 * MB);
    unsigned short* Thi  = (unsigned short*)(ws + 66 * MB);
    unsigned short* Tlo  = (unsigned short*)(ws + 68 * MB);

    // 1) fused splits (X -> hi/lo/i8, Wq/Wk -> hi/lo)
    split_all<<<6144, 256, 0, stream>>>(
        (const float4*)X, (const float4*)Wq, (const float4*)Wk,
        (ushort4*)Xhi, (ushort4*)Xlo, (char4*)Xi8,
        (ushort4*)Wqhi, (ushort4*)Wqlo, (ushort4*)Wkhi, (ushort4*)Wklo);

    // 2) T = Wk @ Wq^T (= M^T), 3-pass split, BK=64 -> split bf16
    gemm_mfma<64, 64, 3, 1, 2><<<dim3(16, 16), 256, 0, stream>>>(
        Wkhi, Wklo, Wqhi, Wqlo, nullptr, Thi, Tlo, nullptr,
        EMBED, EMBED, EMBED, EMBED, 1.0f);

    // 3) Qf = X @ T^T (= X @ M), 3-pass split, BM=128 (measured-best tile)
    gemm_mfma<128, 64, 3, 2, 2><<<dim3(16, 32), 256, 0, stream>>>(
        Xhi, Xlo, Thi, Tlo, Qf, nullptr, nullptr, Qi8,
        EMBED, EMBED, EMBED, EMBED, 1.0f);

    // 4) i8 cheap scores (128x128, BK=128) + write-only candidate selection
    gemm_i8_scores<<<dim3(32, 32), 256, 0, stream>>>(Qi8, Xi8, tmax, cnts, cand);

    // 5) exact sparse softmax + gather
    sparse_out<<<NTOK, 256, 0, stream>>>(tmax, cnts, cand, Qf, X, out);
}